// Round 10
// baseline (140.946 us; speedup 1.0000x reference)
//
#include <hip/hip_runtime.h>
#include <hip/hip_bf16.h>
#include <stdint.h>

typedef __hip_bfloat16 bf16;
typedef float f32x4 __attribute__((ext_vector_type(4)));
typedef short bf16x8 __attribute__((ext_vector_type(8)));

#define NB 16384
#define NA 16
#define ND 512
#define NH 512
#define TR 80  // rows/tile: ~26 tiles/XCD-pair <= 32 CUs -> all resident

// workspace layout (bytes)
#define W1S_OFF 0u
#define W2S_OFF 8388608u
#define PERM_OFF 16777216u
#define META_OFF 16842752u
// meta ints: [0..15]=cnt, [16..31]=off

__device__ __forceinline__ unsigned short f2b(float x) {
  unsigned int b = __float_as_uint(x);
  return (unsigned short)((b + 0x7FFFu + ((b >> 16) & 1u)) >> 16);  // RNE
}

// ---------------- prep: W transpose+cast (blocks 0..2047) + zero-atomic meta (block 2048) --
// Weight layout per action: blob[(h>>4)*16 + (k>>5)] of 1KB; byte =
// ((k>>3)&3)*256 + (h&15)*16 + (k&7)*2.  A wave's MFMA A-fragment = 1KB contiguous.
__global__ __launch_bounds__(256) void k_prep(const float* __restrict__ W1,
                                              const float* __restrict__ W2,
                                              bf16* __restrict__ W1s,
                                              bf16* __restrict__ W2s,
                                              const int* __restrict__ act,
                                              int* __restrict__ meta,
                                              int* __restrict__ perm) {
  if (blockIdx.x == 2048) {
    __shared__ unsigned short pfx[64][4][16];  // per (iter, wave, action) count -> prefix
    __shared__ int cnt[16], off[16];
    int tid = threadIdx.x;
    int wv = tid >> 6, lane = tid & 63;
    unsigned long long below = (lane == 0) ? 0ull : (~0ull >> (64 - lane));
    for (int i = tid; i < 2048; i += 256) ((unsigned int*)pfx)[i] = 0u;
    __syncthreads();
    for (int i = 0; i < 64; ++i) {
      int a = act[tid + (i << 8)] & 15;
      unsigned long long m = ~0ull;
#pragma unroll
      for (int b = 0; b < 4; ++b) {
        unsigned long long bal = __ballot((a >> b) & 1);
        m &= ((a >> b) & 1) ? bal : ~bal;
      }
      if (lane == (__ffsll((unsigned long long)m) - 1))
        pfx[i][wv][a] = (unsigned short)__popcll(m);
    }
    __syncthreads();
    if (tid < 16) {
      int run = 0;
      for (int i = 0; i < 64; ++i)
#pragma unroll
        for (int v = 0; v < 4; ++v) {
          int t = pfx[i][v][tid];
          pfx[i][v][tid] = (unsigned short)run;
          run += t;
        }
      cnt[tid] = run;
    }
    __syncthreads();
    if (tid == 0) {
      int o = 0;
      for (int aa = 0; aa < 16; ++aa) {
        off[aa] = o;
        o += cnt[aa];
      }
    }
    __syncthreads();
    for (int i = 0; i < 64; ++i) {
      int idx = tid + (i << 8);
      int a = act[idx] & 15;
      unsigned long long m = ~0ull;
#pragma unroll
      for (int b = 0; b < 4; ++b) {
        unsigned long long bal = __ballot((a >> b) & 1);
        m &= ((a >> b) & 1) ? bal : ~bal;
      }
      int rank = (int)__popcll(m & below);
      perm[off[a] + (int)pfx[i][wv][a] + rank] = idx;
    }
    if (tid < 16) {
      meta[tid] = cnt[tid];
      meta[16 + tid] = off[tid];
    }
    return;
  }
  __shared__ float tile[64][65];
  int blk = blockIdx.x;          // 0..2047
  int m = blk >> 6;              // matrix 0..31
  int tl = blk & 63;
  int td = tl >> 3, th = tl & 7;
  const float* src = (m < NA) ? (W1 + (size_t)m * (ND * NH)) : (W2 + (size_t)(m - NA) * (ND * NH));
  char* dstb = (m < NA) ? ((char*)W1s + ((size_t)m << 19)) : ((char*)W2s + ((size_t)(m - NA) << 19));
  int t = threadIdx.x;
  int r = t >> 2, c0 = (t & 3) << 4;
  const float* sp = src + (size_t)(td * 64 + r) * NH + th * 64 + c0;
  float4 v0 = ((const float4*)sp)[0];
  float4 v1 = ((const float4*)sp)[1];
  float4 v2 = ((const float4*)sp)[2];
  float4 v3 = ((const float4*)sp)[3];
  float* tr = &tile[r][c0];
  tr[0] = v0.x; tr[1] = v0.y; tr[2] = v0.z; tr[3] = v0.w;
  tr[4] = v1.x; tr[5] = v1.y; tr[6] = v1.z; tr[7] = v1.w;
  tr[8] = v2.x; tr[9] = v2.y; tr[10] = v2.z; tr[11] = v2.w;
  tr[12] = v3.x; tr[13] = v3.y; tr[14] = v3.z; tr[15] = v3.w;
  __syncthreads();
  int hloc = t >> 2, dc = (t & 3) << 4;
  int h = th * 64 + hloc;
  int K0 = td * 64 + dc;
  union { unsigned short us[16]; uint4 q[2]; } u;
#pragma unroll
  for (int i = 0; i < 16; ++i) u.us[i] = f2b(tile[dc + i][hloc]);
  size_t ab = (size_t)((h >> 4) * 16 + (K0 >> 5)) * 1024 + (size_t)(h & 15) * 16;
  *(uint4*)(dstb + ab + (((K0 >> 3) & 3) << 8)) = u.q[0];
  *(uint4*)(dstb + ab + ((((K0 >> 3) + 1) & 3) << 8)) = u.q[1];
}

// ---------------- fused grouped MLP (template ablation) ----------------
// V=0 full; V=1 no weight refills (A regs reused); V=2 no MFMA (loads kept live).
// All write `out`; V0 runs LAST and rewrites every element -> final output correct.
template <int V>
__global__ __launch_bounds__(512, 2) void k_mainT(
    const float* __restrict__ state, const float* __restrict__ b1,
    const float* __restrict__ b2, const float* __restrict__ W3,
    const float* __restrict__ b3, const bf16* __restrict__ W1s,
    const bf16* __restrict__ W2s, const int* __restrict__ perm,
    const int* __restrict__ meta, float* __restrict__ out) {
  extern __shared__ char smem[];
  char* Xs = smem;
  float* outbuf = (float*)(smem + 81920);

  int bid = blockIdx.x;
  int xcd = bid & 7, slot = bid >> 3;
  int a0 = xcd << 1;
  int n0 = meta[a0], n1 = meta[a0 + 1];
  int nt0 = (n0 + TR - 1) / TR, nt1 = (n1 + TR - 1) / TR;
  int a, t;
  if (slot < nt0) {
    a = a0; t = slot;
  } else if (slot < nt0 + nt1) {
    a = a0 + 1; t = slot - nt0;
  } else {
    return;
  }
  int rowbase = meta[16 + a] + t * TR;
  int nrows = meta[a] - t * TR;
  nrows = nrows > TR ? TR : nrows;

  int tid = threadIdx.x;
  int lane = tid & 63;
  int w = tid >> 6;
  int l15 = lane & 15, l4 = lane >> 4;

  bf16x8 A[4][4];
  bf16x8 Bc[5], Bn[5];
  const char* Wl = (const char*)W1s + ((size_t)a << 19) + (w << 16) + (lane << 4);
#pragma unroll
  for (int s = 0; s < 4; ++s)
#pragma unroll
    for (int hf = 0; hf < 4; ++hf)
      A[s][hf] = *(const bf16x8*)(Wl + hf * 16384 + s * 1024);

  // ---- stage X tile -> LDS bf16, swizzle byte ^= (row&7)<<4 ----
  {
#pragma unroll
    for (int it = 0; it < 20; ++it) {
      int c = tid + (it << 9);
      int row = c >> 7, chunk = c & 127;
      int gr = (row < nrows) ? perm[rowbase + row] : -1;
      float4 v = make_float4(0.f, 0.f, 0.f, 0.f);
      if (gr >= 0) v = *(const float4*)(state + (size_t)gr * ND + (chunk << 2));
      uint2 pk;
      pk.x = (unsigned)f2b(v.x) | ((unsigned)f2b(v.y) << 16);
      pk.y = (unsigned)f2b(v.z) | ((unsigned)f2b(v.w) << 16);
      *(uint2*)(Xs + row * 1024 + ((chunk << 3) ^ ((row & 7) << 4))) = pk;
    }
  }
  __syncthreads();

  uint2 h1p[20];

  // ---- layer 1 ----
  {
    f32x4 acc[4][5] = {};
#pragma unroll
    for (int bf = 0; bf < 5; ++bf) {
      int b = (bf << 4) + l15;
      Bc[bf] = *(const bf16x8*)(Xs + b * 1024 + ((l4 << 4) ^ ((b & 7) << 4)));
    }
#pragma unroll
    for (int ks = 0; ks < 16; ++ks) {
      if (ks < 15) {
#pragma unroll
        for (int bf = 0; bf < 5; ++bf) {
          int b = (bf << 4) + l15;
          Bn[bf] = *(const bf16x8*)(Xs + b * 1024 + ((((ks + 1) << 6) + (l4 << 4)) ^ ((b & 7) << 4)));
        }
      }
      if (V == 2) {
#pragma unroll
        for (int hf = 0; hf < 4; ++hf) asm volatile("" ::"v"(A[ks & 3][hf]));
#pragma unroll
        for (int bf = 0; bf < 5; ++bf) asm volatile("" ::"v"(Bc[bf]));
      } else {
#pragma unroll
        for (int hf = 0; hf < 4; ++hf)
#pragma unroll
          for (int bf = 0; bf < 5; ++bf)
            acc[hf][bf] = __builtin_amdgcn_mfma_f32_16x16x32_bf16(A[ks & 3][hf], Bc[bf], acc[hf][bf], 0, 0, 0);
      }
      if (V != 1 && ks < 12) {
#pragma unroll
        for (int hf = 0; hf < 4; ++hf)
          A[ks & 3][hf] = *(const bf16x8*)(Wl + hf * 16384 + (ks + 4) * 1024);
      }
#pragma unroll
      for (int bf = 0; bf < 5; ++bf) Bc[bf] = Bn[bf];
    }
    const char* Wl2 = (const char*)W2s + ((size_t)a << 19) + (w << 16) + (lane << 4);
    if (V != 1) {
#pragma unroll
      for (int s = 0; s < 4; ++s)
#pragma unroll
        for (int hf = 0; hf < 4; ++hf)
          A[s][hf] = *(const bf16x8*)(Wl2 + hf * 16384 + s * 1024);
    }
#pragma unroll
    for (int hf = 0; hf < 4; ++hf) {
      int hb = (w << 6) + (hf << 4) + (l4 << 2);
      float4 bias = *(const float4*)(b1 + (a << 9) + hb);
#pragma unroll
      for (int bf = 0; bf < 5; ++bf) {
        float x0 = fmaxf(acc[hf][bf][0] + bias.x, 0.f);
        float x1 = fmaxf(acc[hf][bf][1] + bias.y, 0.f);
        float x2 = fmaxf(acc[hf][bf][2] + bias.z, 0.f);
        float x3 = fmaxf(acc[hf][bf][3] + bias.w, 0.f);
        h1p[hf * 5 + bf].x = (unsigned)f2b(x0) | ((unsigned)f2b(x1) << 16);
        h1p[hf * 5 + bf].y = (unsigned)f2b(x2) | ((unsigned)f2b(x3) << 16);
      }
    }
  }
  __syncthreads();
#pragma unroll
  for (int hf = 0; hf < 4; ++hf) {
    int hb2 = ((w << 6) + (hf << 4) + (l4 << 2)) << 1;
#pragma unroll
    for (int bf = 0; bf < 5; ++bf) {
      int b = (bf << 4) + l15;
      *(uint2*)(Xs + b * 1024 + (hb2 ^ ((b & 7) << 4))) = h1p[hf * 5 + bf];
    }
  }
  __syncthreads();

  // ---- layer 2 + fused layer 3 ----
  {
    f32x4 acc[4][5] = {};
    const char* Wl2 = (const char*)W2s + ((size_t)a << 19) + (w << 16) + (lane << 4);
#pragma unroll
    for (int bf = 0; bf < 5; ++bf) {
      int b = (bf << 4) + l15;
      Bc[bf] = *(const bf16x8*)(Xs + b * 1024 + ((l4 << 4) ^ ((b & 7) << 4)));
    }
#pragma unroll
    for (int ks = 0; ks < 16; ++ks) {
      if (ks < 15) {
#pragma unroll
        for (int bf = 0; bf < 5; ++bf) {
          int b = (bf << 4) + l15;
          Bn[bf] = *(const bf16x8*)(Xs + b * 1024 + ((((ks + 1) << 6) + (l4 << 4)) ^ ((b & 7) << 4)));
        }
      }
      if (V == 2) {
#pragma unroll
        for (int hf = 0; hf < 4; ++hf) asm volatile("" ::"v"(A[ks & 3][hf]));
#pragma unroll
        for (int bf = 0; bf < 5; ++bf) asm volatile("" ::"v"(Bc[bf]));
      } else {
#pragma unroll
        for (int hf = 0; hf < 4; ++hf)
#pragma unroll
          for (int bf = 0; bf < 5; ++bf)
            acc[hf][bf] = __builtin_amdgcn_mfma_f32_16x16x32_bf16(A[ks & 3][hf], Bc[bf], acc[hf][bf], 0, 0, 0);
      }
      if (V != 1 && ks < 12) {
#pragma unroll
        for (int hf = 0; hf < 4; ++hf)
          A[ks & 3][hf] = *(const bf16x8*)(Wl2 + hf * 16384 + (ks + 4) * 1024);
      }
#pragma unroll
      for (int bf = 0; bf < 5; ++bf) Bc[bf] = Bn[bf];
    }
    float part[5] = {0.f, 0.f, 0.f, 0.f, 0.f};
#pragma unroll
    for (int hf = 0; hf < 4; ++hf) {
      int hb = (w << 6) + (hf << 4) + (l4 << 2);
      float4 bias = *(const float4*)(b2 + (a << 9) + hb);
      float4 w3v = *(const float4*)(W3 + (a << 9) + hb);
#pragma unroll
      for (int bf = 0; bf < 5; ++bf) {
        part[bf] += fmaxf(acc[hf][bf][0] + bias.x, 0.f) * w3v.x +
                    fmaxf(acc[hf][bf][1] + bias.y, 0.f) * w3v.y +
                    fmaxf(acc[hf][bf][2] + bias.z, 0.f) * w3v.z +
                    fmaxf(acc[hf][bf][3] + bias.w, 0.f) * w3v.w;
      }
    }
#pragma unroll
    for (int bf = 0; bf < 5; ++bf) {
      float p = part[bf];
      p += __shfl_xor(p, 16);
      p += __shfl_xor(p, 32);
      if (l4 == 0) outbuf[w * TR + (bf << 4) + l15] = p;
    }
  }
  __syncthreads();
  if (tid < nrows) {
    float s = b3[a];
#pragma unroll
    for (int ww = 0; ww < 8; ++ww) s += outbuf[ww * TR + tid];
    out[perm[rowbase + tid]] = s;
  }
}

extern "C" void kernel_launch(void* const* d_in, const int* in_sizes, int n_in,
                              void* d_out, int out_size, void* d_ws, size_t ws_size,
                              hipStream_t stream) {
  const float* state = (const float*)d_in[0];
  const float* W1 = (const float*)d_in[1];
  const float* b1 = (const float*)d_in[2];
  const float* W2 = (const float*)d_in[3];
  const float* b2 = (const float*)d_in[4];
  const float* W3 = (const float*)d_in[5];
  const float* b3 = (const float*)d_in[6];
  const int* actions = (const int*)d_in[7];
  float* out = (float*)d_out;
  char* ws = (char*)d_ws;
  bf16* W1s = (bf16*)(ws + W1S_OFF);
  bf16* W2s = (bf16*)(ws + W2S_OFF);
  int* perm = (int*)(ws + PERM_OFF);
  int* meta = (int*)(ws + META_OFF);

  k_prep<<<2049, 256, 0, stream>>>(W1, W2, W1s, W2s, actions, meta, perm);
  hipFuncSetAttribute((const void*)k_mainT<1>, hipFuncAttributeMaxDynamicSharedMemorySize, 84480);
  hipFuncSetAttribute((const void*)k_mainT<2>, hipFuncAttributeMaxDynamicSharedMemorySize, 84480);
  hipFuncSetAttribute((const void*)k_mainT<0>, hipFuncAttributeMaxDynamicSharedMemorySize, 84480);
  // ablation probes (outputs overwritten by V0 below)
  k_mainT<1><<<512, 512, 84480, stream>>>(state, b1, b2, W3, b3, W1s, W2s, perm, meta, out);
  k_mainT<2><<<512, 512, 84480, stream>>>(state, b1, b2, W3, b3, W1s, W2s, perm, meta, out);
  // the real kernel (runs last; writes every output element)
  k_mainT<0><<<512, 512, 84480, stream>>>(state, b1, b2, W3, b3, W1s, W2s, perm, meta, out);
}

// Round 11
// 78.190 us; speedup vs baseline: 1.8026x; 1.8026x over previous
//
#include <hip/hip_runtime.h>
#include <hip/hip_bf16.h>
#include <stdint.h>

typedef __hip_bfloat16 bf16;
typedef float f32x4 __attribute__((ext_vector_type(4)));
typedef short bf16x8 __attribute__((ext_vector_type(8)));

#define NB 16384
#define NA 16
#define ND 512
#define NH 512
#define TR 80  // rows/tile: 13 tiles/action, 26/XCD-pair <= 32 CUs -> all resident, no tail

// workspace layout (bytes)
#define W1S_OFF 0u
#define W2S_OFF 8388608u
#define PERM_OFF 16777216u
#define META_OFF 16842752u
// meta ints: [0..15]=cnt, [16..31]=off

__device__ __forceinline__ unsigned short f2b(float x) {
  unsigned int b = __float_as_uint(x);
  return (unsigned short)((b + 0x7FFFu + ((b >> 16) & 1u)) >> 16);  // RNE
}

// ---------------- prep: W transpose+cast (blocks 0..2047) + zero-atomic meta (block 2048) --
// Weight layout per action: blob[(h>>4)*16 + (k>>5)] of 1KB; byte =
// ((k>>3)&3)*256 + (h&15)*16 + (k&7)*2.  Writer: wave v emits whole blobs, lane l
// writes blob+l*16 -> fully coalesced 1KB stores (was: 16B chunks scattered 1KB apart).
__global__ __launch_bounds__(256) void k_prep(const float* __restrict__ W1,
                                              const float* __restrict__ W2,
                                              bf16* __restrict__ W1s,
                                              bf16* __restrict__ W2s,
                                              const int* __restrict__ act,
                                              int* __restrict__ meta,
                                              int* __restrict__ perm) {
  if (blockIdx.x == 2048) {
    __shared__ unsigned short pfx[64][4][16];
    __shared__ int cnt[16], off[16];
    int tid = threadIdx.x;
    int wv = tid >> 6, lane = tid & 63;
    unsigned long long below = (lane == 0) ? 0ull : (~0ull >> (64 - lane));
    for (int i = tid; i < 2048; i += 256) ((unsigned int*)pfx)[i] = 0u;
    __syncthreads();
    for (int i = 0; i < 64; ++i) {
      int a = act[tid + (i << 8)] & 15;
      unsigned long long m = ~0ull;
#pragma unroll
      for (int b = 0; b < 4; ++b) {
        unsigned long long bal = __ballot((a >> b) & 1);
        m &= ((a >> b) & 1) ? bal : ~bal;
      }
      if (lane == (__ffsll((unsigned long long)m) - 1))
        pfx[i][wv][a] = (unsigned short)__popcll(m);
    }
    __syncthreads();
    if (tid < 16) {
      int run = 0;
      for (int i = 0; i < 64; ++i)
#pragma unroll
        for (int v = 0; v < 4; ++v) {
          int t = pfx[i][v][tid];
          pfx[i][v][tid] = (unsigned short)run;
          run += t;
        }
      cnt[tid] = run;
    }
    __syncthreads();
    if (tid == 0) {
      int o = 0;
      for (int aa = 0; aa < 16; ++aa) {
        off[aa] = o;
        o += cnt[aa];
      }
    }
    __syncthreads();
    for (int i = 0; i < 64; ++i) {
      int idx = tid + (i << 8);
      int a = act[idx] & 15;
      unsigned long long m = ~0ull;
#pragma unroll
      for (int b = 0; b < 4; ++b) {
        unsigned long long bal = __ballot((a >> b) & 1);
        m &= ((a >> b) & 1) ? bal : ~bal;
      }
      int rank = (int)__popcll(m & below);
      perm[off[a] + (int)pfx[i][wv][a] + rank] = idx;
    }
    if (tid < 16) {
      meta[tid] = cnt[tid];
      meta[16 + tid] = off[tid];
    }
    return;
  }
  __shared__ float tile[64][65];
  int blk = blockIdx.x;          // 0..2047
  int m = blk >> 6;              // matrix 0..31
  int tl = blk & 63;
  int td = tl >> 3, th = tl & 7; // td: k-tile, th: h-tile
  const float* src = (m < NA) ? (W1 + (size_t)m * (ND * NH)) : (W2 + (size_t)(m - NA) * (ND * NH));
  char* dstb = (m < NA) ? ((char*)W1s + ((size_t)m << 19)) : ((char*)W2s + ((size_t)(m - NA) << 19));
  int t = threadIdx.x;
  int r = t >> 2, c0 = (t & 3) << 4;
  const float* sp = src + (size_t)(td * 64 + r) * NH + th * 64 + c0;
  float4 v0 = ((const float4*)sp)[0];
  float4 v1 = ((const float4*)sp)[1];
  float4 v2 = ((const float4*)sp)[2];
  float4 v3 = ((const float4*)sp)[3];
  float* tr = &tile[r][c0];
  tr[0] = v0.x; tr[1] = v0.y; tr[2] = v0.z; tr[3] = v0.w;
  tr[4] = v1.x; tr[5] = v1.y; tr[6] = v1.z; tr[7] = v1.w;
  tr[8] = v2.x; tr[9] = v2.y; tr[10] = v2.z; tr[11] = v2.w;
  tr[12] = v3.x; tr[13] = v3.y; tr[14] = v3.z; tr[15] = v3.w;
  __syncthreads();
  // writer: wave wv handles h-subtile wv; kc in {0,1}; lane l writes blob + l*16
  int wv = t >> 6, l = t & 63;
  int l15b = l & 15, l4b = l >> 4;
#pragma unroll
  for (int kc = 0; kc < 2; ++kc) {
    union { unsigned short us[8]; uint4 q; } u;
#pragma unroll
    for (int i = 0; i < 8; ++i)
      u.us[i] = f2b(tile[kc * 32 + l4b * 8 + i][wv * 16 + l15b]);
    int hb = th * 4 + wv;   // global h>>4
    int kb = td * 2 + kc;   // global k>>5
    *(uint4*)(dstb + ((size_t)(hb * 16 + kb) << 10) + (l << 4)) = u.q;
  }
}

// ---------------- fused grouped MLP ----------------
// XCD x (bid&7) owns actions 2x,2x+1 (2MB L2 set). Grid 256 = 32 slots/XCD, 26 tiles/pair.
// Block: 80-row tile, 1024 threads = 16 waves (4/SIMD); wave w owns h [w*32, w*32+32).
// Small per-wave regs (A[2][2] depth-2 pipeline, acc[2][5]) to fit the 128-VGPR cap.
// LDS: Xs 80KB @0 (X, then h1 via register round-trip), outbuf 5KB @81920.
__global__ __launch_bounds__(1024) void k_main(
    const float* __restrict__ state, const float* __restrict__ b1,
    const float* __restrict__ b2, const float* __restrict__ W3,
    const float* __restrict__ b3, const bf16* __restrict__ W1s,
    const bf16* __restrict__ W2s, const int* __restrict__ perm,
    const int* __restrict__ meta, float* __restrict__ out) {
  extern __shared__ char smem[];
  char* Xs = smem;
  float* outbuf = (float*)(smem + 81920);

  int bid = blockIdx.x;
  int xcd = bid & 7, slot = bid >> 3;
  int a0 = xcd << 1;
  int n0 = meta[a0], n1 = meta[a0 + 1];
  int nt0 = (n0 + TR - 1) / TR, nt1 = (n1 + TR - 1) / TR;
  int a, t;
  if (slot < nt0) {
    a = a0; t = slot;
  } else if (slot < nt0 + nt1) {
    a = a0 + 1; t = slot - nt0;
  } else {
    return;
  }
  int rowbase = meta[16 + a] + t * TR;
  int nrows = meta[a] - t * TR;
  nrows = nrows > TR ? TR : nrows;

  int tid = threadIdx.x;
  int lane = tid & 63;
  int w = tid >> 6;  // 0..15
  int l15 = lane & 15, l4 = lane >> 4;

  // A blob addr: base + ((h>>4)*16 + ks)*1024 + lane*16, h>>4 = w*2 + hf
  const char* Wl = (const char*)W1s + ((size_t)a << 19) + (w << 15) + (lane << 4);
  const char* Wl2 = (const char*)W2s + ((size_t)a << 19) + (w << 15) + (lane << 4);

  bf16x8 A[2][2];  // [ks&1][hf] depth-2 pipeline
  bf16x8 Bc[5], Bn[5];
#pragma unroll
  for (int s = 0; s < 2; ++s)
#pragma unroll
    for (int hf = 0; hf < 2; ++hf)
      A[s][hf] = *(const bf16x8*)(Wl + (hf << 14) + (s << 10));

  // ---- stage X tile -> LDS bf16, swizzle byte ^= (row&7)<<4 ----
  {
#pragma unroll
    for (int it = 0; it < 10; ++it) {
      int c = tid + (it << 10);      // 0..10239
      int row = c >> 7, chunk = c & 127;
      int gr = (row < nrows) ? perm[rowbase + row] : -1;
      float4 v = make_float4(0.f, 0.f, 0.f, 0.f);
      if (gr >= 0) v = *(const float4*)(state + (size_t)gr * ND + (chunk << 2));
      uint2 pk;
      pk.x = (unsigned)f2b(v.x) | ((unsigned)f2b(v.y) << 16);
      pk.y = (unsigned)f2b(v.z) | ((unsigned)f2b(v.w) << 16);
      *(uint2*)(Xs + row * 1024 + ((chunk << 3) ^ ((row & 7) << 4))) = pk;
    }
  }
  __syncthreads();

  uint2 h1p[10];

  // ---- layer 1: h1 = relu(X @ W1 + b1), [h][b], h1 kept in registers ----
  {
    f32x4 acc[2][5] = {};
#pragma unroll
    for (int bf = 0; bf < 5; ++bf) {
      int b = (bf << 4) + l15;
      Bc[bf] = *(const bf16x8*)(Xs + b * 1024 + ((l4 << 4) ^ ((b & 7) << 4)));
    }
#pragma unroll
    for (int ks = 0; ks < 16; ++ks) {
      if (ks < 15) {
#pragma unroll
        for (int bf = 0; bf < 5; ++bf) {
          int b = (bf << 4) + l15;
          Bn[bf] = *(const bf16x8*)(Xs + b * 1024 + ((((ks + 1) << 6) + (l4 << 4)) ^ ((b & 7) << 4)));
        }
      }
#pragma unroll
      for (int hf = 0; hf < 2; ++hf)
#pragma unroll
        for (int bf = 0; bf < 5; ++bf)
          acc[hf][bf] = __builtin_amdgcn_mfma_f32_16x16x32_bf16(A[ks & 1][hf], Bc[bf], acc[hf][bf], 0, 0, 0);
      if (ks < 14) {
#pragma unroll
        for (int hf = 0; hf < 2; ++hf)
          A[ks & 1][hf] = *(const bf16x8*)(Wl + (hf << 14) + ((ks + 2) << 10));
      }
#pragma unroll
      for (int bf = 0; bf < 5; ++bf) Bc[bf] = Bn[bf];
    }
    // layer-2 A preloads; latency hides under epilogue + barriers
#pragma unroll
    for (int s = 0; s < 2; ++s)
#pragma unroll
      for (int hf = 0; hf < 2; ++hf)
        A[s][hf] = *(const bf16x8*)(Wl2 + (hf << 14) + (s << 10));
    // epilogue: bias + relu + pack bf16 into registers
#pragma unroll
    for (int hf = 0; hf < 2; ++hf) {
      int hb = (w << 5) + (hf << 4) + (l4 << 2);
      float4 bias = *(const float4*)(b1 + (a << 9) + hb);
#pragma unroll
      for (int bf = 0; bf < 5; ++bf) {
        float x0 = fmaxf(acc[hf][bf][0] + bias.x, 0.f);
        float x1 = fmaxf(acc[hf][bf][1] + bias.y, 0.f);
        float x2 = fmaxf(acc[hf][bf][2] + bias.z, 0.f);
        float x3 = fmaxf(acc[hf][bf][3] + bias.w, 0.f);
        h1p[hf * 5 + bf].x = (unsigned)f2b(x0) | ((unsigned)f2b(x1) << 16);
        h1p[hf * 5 + bf].y = (unsigned)f2b(x2) | ((unsigned)f2b(x3) << 16);
      }
    }
  }
  __syncthreads();  // all waves done reading X
#pragma unroll
  for (int hf = 0; hf < 2; ++hf) {
    int hb2 = ((w << 5) + (hf << 4) + (l4 << 2)) << 1;  // byte offset within row
#pragma unroll
    for (int bf = 0; bf < 5; ++bf) {
      int b = (bf << 4) + l15;
      *(uint2*)(Xs + b * 1024 + (hb2 ^ ((b & 7) << 4))) = h1p[hf * 5 + bf];
    }
  }
  __syncthreads();

  // ---- layer 2 + fused layer 3: out = relu(h1 @ W2 + b2) . W3 + b3 ----
  {
    f32x4 acc[2][5] = {};
#pragma unroll
    for (int bf = 0; bf < 5; ++bf) {
      int b = (bf << 4) + l15;
      Bc[bf] = *(const bf16x8*)(Xs + b * 1024 + ((l4 << 4) ^ ((b & 7) << 4)));
    }
#pragma unroll
    for (int ks = 0; ks < 16; ++ks) {
      if (ks < 15) {
#pragma unroll
        for (int bf = 0; bf < 5; ++bf) {
          int b = (bf << 4) + l15;
          Bn[bf] = *(const bf16x8*)(Xs + b * 1024 + ((((ks + 1) << 6) + (l4 << 4)) ^ ((b & 7) << 4)));
        }
      }
#pragma unroll
      for (int hf = 0; hf < 2; ++hf)
#pragma unroll
        for (int bf = 0; bf < 5; ++bf)
          acc[hf][bf] = __builtin_amdgcn_mfma_f32_16x16x32_bf16(A[ks & 1][hf], Bc[bf], acc[hf][bf], 0, 0, 0);
      if (ks < 14) {
#pragma unroll
        for (int hf = 0; hf < 2; ++hf)
          A[ks & 1][hf] = *(const bf16x8*)(Wl2 + (hf << 14) + ((ks + 2) << 10));
      }
#pragma unroll
      for (int bf = 0; bf < 5; ++bf) Bc[bf] = Bn[bf];
    }
    float part[5] = {0.f, 0.f, 0.f, 0.f, 0.f};
#pragma unroll
    for (int hf = 0; hf < 2; ++hf) {
      int hb = (w << 5) + (hf << 4) + (l4 << 2);
      float4 bias = *(const float4*)(b2 + (a << 9) + hb);
      float4 w3v = *(const float4*)(W3 + (a << 9) + hb);
#pragma unroll
      for (int bf = 0; bf < 5; ++bf) {
        part[bf] += fmaxf(acc[hf][bf][0] + bias.x, 0.f) * w3v.x +
                    fmaxf(acc[hf][bf][1] + bias.y, 0.f) * w3v.y +
                    fmaxf(acc[hf][bf][2] + bias.z, 0.f) * w3v.z +
                    fmaxf(acc[hf][bf][3] + bias.w, 0.f) * w3v.w;
      }
    }
#pragma unroll
    for (int bf = 0; bf < 5; ++bf) {
      float p = part[bf];
      p += __shfl_xor(p, 16);
      p += __shfl_xor(p, 32);
      if (l4 == 0) outbuf[w * TR + (bf << 4) + l15] = p;
    }
  }
  __syncthreads();
  if (tid < nrows) {
    float s = b3[a];
#pragma unroll
    for (int ww = 0; ww < 16; ++ww) s += outbuf[ww * TR + tid];
    out[perm[rowbase + tid]] = s;
  }
}

extern "C" void kernel_launch(void* const* d_in, const int* in_sizes, int n_in,
                              void* d_out, int out_size, void* d_ws, size_t ws_size,
                              hipStream_t stream) {
  const float* state = (const float*)d_in[0];
  const float* W1 = (const float*)d_in[1];
  const float* b1 = (const float*)d_in[2];
  const float* W2 = (const float*)d_in[3];
  const float* b2 = (const float*)d_in[4];
  const float* W3 = (const float*)d_in[5];
  const float* b3 = (const float*)d_in[6];
  const int* actions = (const int*)d_in[7];
  float* out = (float*)d_out;
  char* ws = (char*)d_ws;
  bf16* W1s = (bf16*)(ws + W1S_OFF);
  bf16* W2s = (bf16*)(ws + W2S_OFF);
  int* perm = (int*)(ws + PERM_OFF);
  int* meta = (int*)(ws + META_OFF);

  k_prep<<<2049, 256, 0, stream>>>(W1, W2, W1s, W2s, actions, meta, perm);
  hipFuncSetAttribute((const void*)k_main, hipFuncAttributeMaxDynamicSharedMemorySize, 87040);
  k_main<<<256, 1024, 87040, stream>>>(state, b1, b2, W3, b3, W1s, W2s, perm, meta, out);
}

// Round 12
// 50.721 us; speedup vs baseline: 2.7789x; 1.5416x over previous
//
#include <hip/hip_runtime.h>
#include <hip/hip_bf16.h>
#include <stdint.h>

typedef __hip_bfloat16 bf16;
typedef float f32x4 __attribute__((ext_vector_type(4)));
typedef short bf16x8 __attribute__((ext_vector_type(8)));

#define NB 16384
#define NA 16
#define ND 512
#define NH 512
#define TR 80  // rows/tile: 13 tiles/action, 26/XCD-pair <= 32 CUs -> all resident, no tail

// workspace layout (bytes)
#define W1S_OFF 0u
#define W2S_OFF 8388608u
#define PERM_OFF 16777216u
#define META_OFF 16842752u
// meta ints: [0..15]=cnt, [16..31]=off

__device__ __forceinline__ unsigned short f2b(float x) {
  unsigned int b = __float_as_uint(x);
  return (unsigned short)((b + 0x7FFFu + ((b >> 16) & 1u)) >> 16);  // RNE
}

// ---------------- prep: W transpose+cast (blocks 0..2047) + parallel meta (block 2048) -----
// Weight layout per action: blob[(h>>4)*16 + (k>>5)] of 1KB; byte =
// ((k>>3)&3)*256 + (h&15)*16 + (k&7)*2.  Transpose writer: wave emits whole blobs
// (lane l writes blob+l*16, coalesced). Meta: per-thread LDS histogram columns +
// wave-parallel shfl-scan + cursor scatter — ~8us, hides under transpose blocks.
__global__ __launch_bounds__(256) void k_prep(const float* __restrict__ W1,
                                              const float* __restrict__ W2,
                                              bf16* __restrict__ W1s,
                                              bf16* __restrict__ W2s,
                                              const int* __restrict__ act,
                                              int* __restrict__ meta,
                                              int* __restrict__ perm) {
  if (blockIdx.x == 2048) {
    __shared__ int hist[16][256];  // [action][thread] cnt -> prefix -> cursor
    __shared__ int off16[16];
    int t = threadIdx.x;
    int lane = t & 63, wv = t >> 6;
#pragma unroll
    for (int i = 0; i < 16; ++i) hist[i][t] = 0;
    __syncthreads();
    // count: thread t owns elements {t + j*256} (coalesced loads)
    for (int j = 0; j < 64; ++j) {
      int a = act[t + (j << 8)] & 15;
      hist[a][t]++;
    }
    __syncthreads();
    // scan: wave wv handles actions 4wv..4wv+3; 256 slots = 4/lane + wave shfl-scan
    for (int q = 0; q < 4; ++q) {
      int a = (wv << 2) + q;
      int base = lane << 2;
      int v0 = hist[a][base + 0];
      int v1 = hist[a][base + 1];
      int v2 = hist[a][base + 2];
      int v3 = hist[a][base + 3];
      int s = v0 + v1 + v2 + v3;
      int incl = s;
#pragma unroll
      for (int d = 1; d < 64; d <<= 1) {
        int y = __shfl_up(incl, d);
        if (lane >= d) incl += y;
      }
      int excl = incl - s;
      hist[a][base + 0] = excl;
      hist[a][base + 1] = excl + v0;
      hist[a][base + 2] = excl + v0 + v1;
      hist[a][base + 3] = excl + v0 + v1 + v2;
      if (lane == 63) off16[a] = incl;  // action total (temp)
    }
    __syncthreads();
    if (t == 0) {
      int o = 0;
      for (int aa = 0; aa < 16; ++aa) {
        int c = off16[aa];
        meta[aa] = c;
        meta[16 + aa] = o;
        off16[aa] = o;
        o += c;
      }
    }
    __syncthreads();
    // scatter: pos = off[a] + prefix-cursor (deterministic; j-order within thread)
    for (int j = 0; j < 64; ++j) {
      int idx = t + (j << 8);
      int a = act[idx] & 15;
      int pos = off16[a] + hist[a][t]++;
      perm[pos] = idx;
    }
    return;
  }
  __shared__ float tile[64][65];
  int blk = blockIdx.x;          // 0..2047
  int m = blk >> 6;              // matrix 0..31
  int tl = blk & 63;
  int td = tl >> 3, th = tl & 7; // td: k-tile, th: h-tile
  const float* src = (m < NA) ? (W1 + (size_t)m * (ND * NH)) : (W2 + (size_t)(m - NA) * (ND * NH));
  char* dstb = (m < NA) ? ((char*)W1s + ((size_t)m << 19)) : ((char*)W2s + ((size_t)(m - NA) << 19));
  int t = threadIdx.x;
  int r = t >> 2, c0 = (t & 3) << 4;
  const float* sp = src + (size_t)(td * 64 + r) * NH + th * 64 + c0;
  float4 v0 = ((const float4*)sp)[0];
  float4 v1 = ((const float4*)sp)[1];
  float4 v2 = ((const float4*)sp)[2];
  float4 v3 = ((const float4*)sp)[3];
  float* tr = &tile[r][c0];
  tr[0] = v0.x; tr[1] = v0.y; tr[2] = v0.z; tr[3] = v0.w;
  tr[4] = v1.x; tr[5] = v1.y; tr[6] = v1.z; tr[7] = v1.w;
  tr[8] = v2.x; tr[9] = v2.y; tr[10] = v2.z; tr[11] = v2.w;
  tr[12] = v3.x; tr[13] = v3.y; tr[14] = v3.z; tr[15] = v3.w;
  __syncthreads();
  // writer: wave wv handles h-subtile wv; kc in {0,1}; lane l writes blob + l*16
  int wv = t >> 6, l = t & 63;
  int l15b = l & 15, l4b = l >> 4;
#pragma unroll
  for (int kc = 0; kc < 2; ++kc) {
    union { unsigned short us[8]; uint4 q; } u;
#pragma unroll
    for (int i = 0; i < 8; ++i)
      u.us[i] = f2b(tile[kc * 32 + l4b * 8 + i][wv * 16 + l15b]);
    int hb = th * 4 + wv;   // global h>>4
    int kb = td * 2 + kc;   // global k>>5
    *(uint4*)(dstb + ((size_t)(hb * 16 + kb) << 10) + (l << 4)) = u.q;
  }
}

// ---------------- fused grouped MLP ----------------
// XCD x (bid&7) owns actions 2x,2x+1 (2MB L2 set). Grid 256 = 32 slots/XCD, 26 tiles/pair.
// Block: 80-row tile, 1024 threads = 16 waves (4/SIMD); wave w owns h [w*32, w*32+32).
// Small per-wave regs (A[2][2] depth-2 pipeline, acc[2][5]) to fit the 128-VGPR cap.
// LDS: Xs 80KB @0 (X, then h1 via register round-trip), outbuf 5KB @81920.
__global__ __launch_bounds__(1024) void k_main(
    const float* __restrict__ state, const float* __restrict__ b1,
    const float* __restrict__ b2, const float* __restrict__ W3,
    const float* __restrict__ b3, const bf16* __restrict__ W1s,
    const bf16* __restrict__ W2s, const int* __restrict__ perm,
    const int* __restrict__ meta, float* __restrict__ out) {
  extern __shared__ char smem[];
  char* Xs = smem;
  float* outbuf = (float*)(smem + 81920);

  int bid = blockIdx.x;
  int xcd = bid & 7, slot = bid >> 3;
  int a0 = xcd << 1;
  int n0 = meta[a0], n1 = meta[a0 + 1];
  int nt0 = (n0 + TR - 1) / TR, nt1 = (n1 + TR - 1) / TR;
  int a, t;
  if (slot < nt0) {
    a = a0; t = slot;
  } else if (slot < nt0 + nt1) {
    a = a0 + 1; t = slot - nt0;
  } else {
    return;
  }
  int rowbase = meta[16 + a] + t * TR;
  int nrows = meta[a] - t * TR;
  nrows = nrows > TR ? TR : nrows;

  int tid = threadIdx.x;
  int lane = tid & 63;
  int w = tid >> 6;  // 0..15
  int l15 = lane & 15, l4 = lane >> 4;

  // A blob addr: base + ((h>>4)*16 + ks)*1024 + lane*16, h>>4 = w*2 + hf
  const char* Wl = (const char*)W1s + ((size_t)a << 19) + (w << 15) + (lane << 4);
  const char* Wl2 = (const char*)W2s + ((size_t)a << 19) + (w << 15) + (lane << 4);

  bf16x8 A[2][2];  // [ks&1][hf] depth-2 pipeline
  bf16x8 Bc[5], Bn[5];
#pragma unroll
  for (int s = 0; s < 2; ++s)
#pragma unroll
    for (int hf = 0; hf < 2; ++hf)
      A[s][hf] = *(const bf16x8*)(Wl + (hf << 14) + (s << 10));

  // ---- stage X tile -> LDS bf16, swizzle byte ^= (row&7)<<4 ----
  {
#pragma unroll
    for (int it = 0; it < 10; ++it) {
      int c = tid + (it << 10);      // 0..10239
      int row = c >> 7, chunk = c & 127;
      int gr = (row < nrows) ? perm[rowbase + row] : -1;
      float4 v = make_float4(0.f, 0.f, 0.f, 0.f);
      if (gr >= 0) v = *(const float4*)(state + (size_t)gr * ND + (chunk << 2));
      uint2 pk;
      pk.x = (unsigned)f2b(v.x) | ((unsigned)f2b(v.y) << 16);
      pk.y = (unsigned)f2b(v.z) | ((unsigned)f2b(v.w) << 16);
      *(uint2*)(Xs + row * 1024 + ((chunk << 3) ^ ((row & 7) << 4))) = pk;
    }
  }
  __syncthreads();

  uint2 h1p[10];

  // ---- layer 1: h1 = relu(X @ W1 + b1), [h][b], h1 kept in registers ----
  {
    f32x4 acc[2][5] = {};
#pragma unroll
    for (int bf = 0; bf < 5; ++bf) {
      int b = (bf << 4) + l15;
      Bc[bf] = *(const bf16x8*)(Xs + b * 1024 + ((l4 << 4) ^ ((b & 7) << 4)));
    }
#pragma unroll
    for (int ks = 0; ks < 16; ++ks) {
      if (ks < 15) {
#pragma unroll
        for (int bf = 0; bf < 5; ++bf) {
          int b = (bf << 4) + l15;
          Bn[bf] = *(const bf16x8*)(Xs + b * 1024 + ((((ks + 1) << 6) + (l4 << 4)) ^ ((b & 7) << 4)));
        }
      }
#pragma unroll
      for (int hf = 0; hf < 2; ++hf)
#pragma unroll
        for (int bf = 0; bf < 5; ++bf)
          acc[hf][bf] = __builtin_amdgcn_mfma_f32_16x16x32_bf16(A[ks & 1][hf], Bc[bf], acc[hf][bf], 0, 0, 0);
      if (ks < 14) {
#pragma unroll
        for (int hf = 0; hf < 2; ++hf)
          A[ks & 1][hf] = *(const bf16x8*)(Wl + (hf << 14) + ((ks + 2) << 10));
      }
#pragma unroll
      for (int bf = 0; bf < 5; ++bf) Bc[bf] = Bn[bf];
    }
    // layer-2 A preloads; latency hides under epilogue + barriers
#pragma unroll
    for (int s = 0; s < 2; ++s)
#pragma unroll
      for (int hf = 0; hf < 2; ++hf)
        A[s][hf] = *(const bf16x8*)(Wl2 + (hf << 14) + (s << 10));
    // epilogue: bias + relu + pack bf16 into registers
#pragma unroll
    for (int hf = 0; hf < 2; ++hf) {
      int hb = (w << 5) + (hf << 4) + (l4 << 2);
      float4 bias = *(const float4*)(b1 + (a << 9) + hb);
#pragma unroll
      for (int bf = 0; bf < 5; ++bf) {
        float x0 = fmaxf(acc[hf][bf][0] + bias.x, 0.f);
        float x1 = fmaxf(acc[hf][bf][1] + bias.y, 0.f);
        float x2 = fmaxf(acc[hf][bf][2] + bias.z, 0.f);
        float x3 = fmaxf(acc[hf][bf][3] + bias.w, 0.f);
        h1p[hf * 5 + bf].x = (unsigned)f2b(x0) | ((unsigned)f2b(x1) << 16);
        h1p[hf * 5 + bf].y = (unsigned)f2b(x2) | ((unsigned)f2b(x3) << 16);
      }
    }
  }
  __syncthreads();  // all waves done reading X
#pragma unroll
  for (int hf = 0; hf < 2; ++hf) {
    int hb2 = ((w << 5) + (hf << 4) + (l4 << 2)) << 1;  // byte offset within row
#pragma unroll
    for (int bf = 0; bf < 5; ++bf) {
      int b = (bf << 4) + l15;
      *(uint2*)(Xs + b * 1024 + (hb2 ^ ((b & 7) << 4))) = h1p[hf * 5 + bf];
    }
  }
  __syncthreads();

  // ---- layer 2 + fused layer 3: out = relu(h1 @ W2 + b2) . W3 + b3 ----
  {
    f32x4 acc[2][5] = {};
#pragma unroll
    for (int bf = 0; bf < 5; ++bf) {
      int b = (bf << 4) + l15;
      Bc[bf] = *(const bf16x8*)(Xs + b * 1024 + ((l4 << 4) ^ ((b & 7) << 4)));
    }
#pragma unroll
    for (int ks = 0; ks < 16; ++ks) {
      if (ks < 15) {
#pragma unroll
        for (int bf = 0; bf < 5; ++bf) {
          int b = (bf << 4) + l15;
          Bn[bf] = *(const bf16x8*)(Xs + b * 1024 + ((((ks + 1) << 6) + (l4 << 4)) ^ ((b & 7) << 4)));
        }
      }
#pragma unroll
      for (int hf = 0; hf < 2; ++hf)
#pragma unroll
        for (int bf = 0; bf < 5; ++bf)
          acc[hf][bf] = __builtin_amdgcn_mfma_f32_16x16x32_bf16(A[ks & 1][hf], Bc[bf], acc[hf][bf], 0, 0, 0);
      if (ks < 14) {
#pragma unroll
        for (int hf = 0; hf < 2; ++hf)
          A[ks & 1][hf] = *(const bf16x8*)(Wl2 + (hf << 14) + ((ks + 2) << 10));
      }
#pragma unroll
      for (int bf = 0; bf < 5; ++bf) Bc[bf] = Bn[bf];
    }
    float part[5] = {0.f, 0.f, 0.f, 0.f, 0.f};
#pragma unroll
    for (int hf = 0; hf < 2; ++hf) {
      int hb = (w << 5) + (hf << 4) + (l4 << 2);
      float4 bias = *(const float4*)(b2 + (a << 9) + hb);
      float4 w3v = *(const float4*)(W3 + (a << 9) + hb);
#pragma unroll
      for (int bf = 0; bf < 5; ++bf) {
        part[bf] += fmaxf(acc[hf][bf][0] + bias.x, 0.f) * w3v.x +
                    fmaxf(acc[hf][bf][1] + bias.y, 0.f) * w3v.y +
                    fmaxf(acc[hf][bf][2] + bias.z, 0.f) * w3v.z +
                    fmaxf(acc[hf][bf][3] + bias.w, 0.f) * w3v.w;
      }
    }
#pragma unroll
    for (int bf = 0; bf < 5; ++bf) {
      float p = part[bf];
      p += __shfl_xor(p, 16);
      p += __shfl_xor(p, 32);
      if (l4 == 0) outbuf[w * TR + (bf << 4) + l15] = p;
    }
  }
  __syncthreads();
  if (tid < nrows) {
    float s = b3[a];
#pragma unroll
    for (int ww = 0; ww < 16; ++ww) s += outbuf[ww * TR + tid];
    out[perm[rowbase + tid]] = s;
  }
}

extern "C" void kernel_launch(void* const* d_in, const int* in_sizes, int n_in,
                              void* d_out, int out_size, void* d_ws, size_t ws_size,
                              hipStream_t stream) {
  const float* state = (const float*)d_in[0];
  const float* W1 = (const float*)d_in[1];
  const float* b1 = (const float*)d_in[2];
  const float* W2 = (const float*)d_in[3];
  const float* b2 = (const float*)d_in[4];
  const float* W3 = (const float*)d_in[5];
  const float* b3 = (const float*)d_in[6];
  const int* actions = (const int*)d_in[7];
  float* out = (float*)d_out;
  char* ws = (char*)d_ws;
  bf16* W1s = (bf16*)(ws + W1S_OFF);
  bf16* W2s = (bf16*)(ws + W2S_OFF);
  int* perm = (int*)(ws + PERM_OFF);
  int* meta = (int*)(ws + META_OFF);

  k_prep<<<2049, 256, 0, stream>>>(W1, W2, W1s, W2s, actions, meta, perm);
  hipFuncSetAttribute((const void*)k_main, hipFuncAttributeMaxDynamicSharedMemorySize, 87040);
  k_main<<<256, 1024, 87040, stream>>>(state, b1, b2, W3, b3, W1s, W2s, perm, meta, out);
}

// Round 13
// 48.632 us; speedup vs baseline: 2.8982x; 1.0430x over previous
//
#include <hip/hip_runtime.h>
#include <hip/hip_bf16.h>
#include <stdint.h>

typedef __hip_bfloat16 bf16;
typedef float f32x4 __attribute__((ext_vector_type(4)));
typedef short bf16x8 __attribute__((ext_vector_type(8)));

#define NB 16384
#define NA 16
#define ND 512
#define NH 512
#define TR 80  // rows/tile: 13 tiles/action, 26/XCD-pair <= 32 CUs -> all resident, no tail

// workspace layout (bytes)
#define W1S_OFF 0u
#define W2S_OFF 8388608u
#define PERM_OFF 16777216u
#define META_OFF 16842752u
// meta ints: [0..15]=cnt, [16..31]=off

__device__ __forceinline__ unsigned short f2b(float x) {
  unsigned int b = __float_as_uint(x);
  return (unsigned short)((b + 0x7FFFu + ((b >> 16) & 1u)) >> 16);  // RNE
}

// ---------------- prep: parallel meta (block 0) + W transpose+cast (blocks 1..2048) --------
// Meta and transpose SHARE one LDS union (16.6 KB -> 8 blocks/CU, single scheduling round).
// Transpose blocks are XCD-pinned: bid&7==x handles actions 2x,2x+1 (W1+W2), so the
// transposed weights are written (and possibly retained) in the consuming XCD's L2.
// Weight layout per action: blob[(h>>4)*16 + (k>>5)] of 1KB; byte =
// ((k>>3)&3)*256 + (h&15)*16 + (k&7)*2.  Wave emits whole blobs (lane l -> blob+l*16).
__global__ __launch_bounds__(256) void k_prep(const float* __restrict__ W1,
                                              const float* __restrict__ W2,
                                              bf16* __restrict__ W1s,
                                              bf16* __restrict__ W2s,
                                              const int* __restrict__ act,
                                              int* __restrict__ meta,
                                              int* __restrict__ perm) {
  __shared__ union {
    float tile[64][65];
    struct { int hist[16][256]; int off16[16]; } m;
  } lds;
  if (blockIdx.x == 0) {
    int t = threadIdx.x;
    int lane = t & 63, wv = t >> 6;
#pragma unroll
    for (int i = 0; i < 16; ++i) lds.m.hist[i][t] = 0;
    __syncthreads();
    // count: thread t owns elements {t + j*256} (coalesced loads)
    for (int j = 0; j < 64; ++j) {
      int a = act[t + (j << 8)] & 15;
      lds.m.hist[a][t]++;
    }
    __syncthreads();
    // scan: wave wv handles actions 4wv..4wv+3; 256 slots = 4/lane + wave shfl-scan
    for (int q = 0; q < 4; ++q) {
      int a = (wv << 2) + q;
      int base = lane << 2;
      int v0 = lds.m.hist[a][base + 0];
      int v1 = lds.m.hist[a][base + 1];
      int v2 = lds.m.hist[a][base + 2];
      int v3 = lds.m.hist[a][base + 3];
      int s = v0 + v1 + v2 + v3;
      int incl = s;
#pragma unroll
      for (int d = 1; d < 64; d <<= 1) {
        int y = __shfl_up(incl, d);
        if (lane >= d) incl += y;
      }
      int excl = incl - s;
      lds.m.hist[a][base + 0] = excl;
      lds.m.hist[a][base + 1] = excl + v0;
      lds.m.hist[a][base + 2] = excl + v0 + v1;
      lds.m.hist[a][base + 3] = excl + v0 + v1 + v2;
      if (lane == 63) lds.m.off16[a] = incl;  // action total (temp)
    }
    __syncthreads();
    if (t == 0) {
      int o = 0;
      for (int aa = 0; aa < 16; ++aa) {
        int c = lds.m.off16[aa];
        meta[aa] = c;
        meta[16 + aa] = o;
        lds.m.off16[aa] = o;
        o += c;
      }
    }
    __syncthreads();
    // scatter: pos = off[a] + prefix-cursor (deterministic; j-order within thread)
    for (int j = 0; j < 64; ++j) {
      int idx = t + (j << 8);
      int a = act[idx] & 15;
      int pos = lds.m.off16[a] + lds.m.hist[a][t]++;
      perm[pos] = idx;
    }
    return;
  }
  int j = blockIdx.x - 1;        // 0..2047
  int xcd = j & 7;
  int job = j >> 3;              // 0..255
  int mi = job >> 6;             // 0..3: W1[2x], W1[2x+1], W2[2x], W2[2x+1]
  int m = (mi < 2) ? ((xcd << 1) + mi) : (NA + (xcd << 1) + (mi - 2));
  int tl = job & 63;
  int td = tl >> 3, th = tl & 7; // td: k-tile, th: h-tile
  const float* src = (m < NA) ? (W1 + (size_t)m * (ND * NH)) : (W2 + (size_t)(m - NA) * (ND * NH));
  char* dstb = (m < NA) ? ((char*)W1s + ((size_t)m << 19)) : ((char*)W2s + ((size_t)(m - NA) << 19));
  int t = threadIdx.x;
  int r = t >> 2, c0 = (t & 3) << 4;
  const float* sp = src + (size_t)(td * 64 + r) * NH + th * 64 + c0;
  float4 v0 = ((const float4*)sp)[0];
  float4 v1 = ((const float4*)sp)[1];
  float4 v2 = ((const float4*)sp)[2];
  float4 v3 = ((const float4*)sp)[3];
  float* tr = &lds.tile[r][c0];
  tr[0] = v0.x; tr[1] = v0.y; tr[2] = v0.z; tr[3] = v0.w;
  tr[4] = v1.x; tr[5] = v1.y; tr[6] = v1.z; tr[7] = v1.w;
  tr[8] = v2.x; tr[9] = v2.y; tr[10] = v2.z; tr[11] = v2.w;
  tr[12] = v3.x; tr[13] = v3.y; tr[14] = v3.z; tr[15] = v3.w;
  __syncthreads();
  // writer: wave wv handles h-subtile wv; kc in {0,1}; lane l writes blob + l*16
  int wv = t >> 6, l = t & 63;
  int l15b = l & 15, l4b = l >> 4;
#pragma unroll
  for (int kc = 0; kc < 2; ++kc) {
    union { unsigned short us[8]; uint4 q; } u;
#pragma unroll
    for (int i = 0; i < 8; ++i)
      u.us[i] = f2b(lds.tile[kc * 32 + l4b * 8 + i][wv * 16 + l15b]);
    int hb = th * 4 + wv;   // global h>>4
    int kb = td * 2 + kc;   // global k>>5
    *(uint4*)(dstb + ((size_t)(hb * 16 + kb) << 10) + (l << 4)) = u.q;
  }
}

// ---------------- fused grouped MLP (unchanged from round 12) ----------------
// XCD x (bid&7) owns actions 2x,2x+1 (2MB L2 set). Grid 256 = 32 slots/XCD, 26 tiles/pair.
// Block: 80-row tile, 1024 threads = 16 waves (4/SIMD); wave w owns h [w*32, w*32+32).
// Small per-wave regs (A[2][2] depth-2 pipeline, acc[2][5]) to fit the 128-VGPR cap.
// LDS: Xs 80KB @0 (X, then h1 via register round-trip), outbuf 5KB @81920.
__global__ __launch_bounds__(1024) void k_main(
    const float* __restrict__ state, const float* __restrict__ b1,
    const float* __restrict__ b2, const float* __restrict__ W3,
    const float* __restrict__ b3, const bf16* __restrict__ W1s,
    const bf16* __restrict__ W2s, const int* __restrict__ perm,
    const int* __restrict__ meta, float* __restrict__ out) {
  extern __shared__ char smem[];
  char* Xs = smem;
  float* outbuf = (float*)(smem + 81920);

  int bid = blockIdx.x;
  int xcd = bid & 7, slot = bid >> 3;
  int a0 = xcd << 1;
  int n0 = meta[a0], n1 = meta[a0 + 1];
  int nt0 = (n0 + TR - 1) / TR, nt1 = (n1 + TR - 1) / TR;
  int a, t;
  if (slot < nt0) {
    a = a0; t = slot;
  } else if (slot < nt0 + nt1) {
    a = a0 + 1; t = slot - nt0;
  } else {
    return;
  }
  int rowbase = meta[16 + a] + t * TR;
  int nrows = meta[a] - t * TR;
  nrows = nrows > TR ? TR : nrows;

  int tid = threadIdx.x;
  int lane = tid & 63;
  int w = tid >> 6;  // 0..15
  int l15 = lane & 15, l4 = lane >> 4;

  // A blob addr: base + ((h>>4)*16 + ks)*1024 + lane*16, h>>4 = w*2 + hf
  const char* Wl = (const char*)W1s + ((size_t)a << 19) + (w << 15) + (lane << 4);
  const char* Wl2 = (const char*)W2s + ((size_t)a << 19) + (w << 15) + (lane << 4);

  bf16x8 A[2][2];  // [ks&1][hf] depth-2 pipeline
  bf16x8 Bc[5], Bn[5];
#pragma unroll
  for (int s = 0; s < 2; ++s)
#pragma unroll
    for (int hf = 0; hf < 2; ++hf)
      A[s][hf] = *(const bf16x8*)(Wl + (hf << 14) + (s << 10));

  // ---- stage X tile -> LDS bf16, swizzle byte ^= (row&7)<<4 ----
  {
#pragma unroll
    for (int it = 0; it < 10; ++it) {
      int c = tid + (it << 10);      // 0..10239
      int row = c >> 7, chunk = c & 127;
      int gr = (row < nrows) ? perm[rowbase + row] : -1;
      float4 v = make_float4(0.f, 0.f, 0.f, 0.f);
      if (gr >= 0) v = *(const float4*)(state + (size_t)gr * ND + (chunk << 2));
      uint2 pk;
      pk.x = (unsigned)f2b(v.x) | ((unsigned)f2b(v.y) << 16);
      pk.y = (unsigned)f2b(v.z) | ((unsigned)f2b(v.w) << 16);
      *(uint2*)(Xs + row * 1024 + ((chunk << 3) ^ ((row & 7) << 4))) = pk;
    }
  }
  __syncthreads();

  uint2 h1p[10];

  // ---- layer 1: h1 = relu(X @ W1 + b1), [h][b], h1 kept in registers ----
  {
    f32x4 acc[2][5] = {};
#pragma unroll
    for (int bf = 0; bf < 5; ++bf) {
      int b = (bf << 4) + l15;
      Bc[bf] = *(const bf16x8*)(Xs + b * 1024 + ((l4 << 4) ^ ((b & 7) << 4)));
    }
#pragma unroll
    for (int ks = 0; ks < 16; ++ks) {
      if (ks < 15) {
#pragma unroll
        for (int bf = 0; bf < 5; ++bf) {
          int b = (bf << 4) + l15;
          Bn[bf] = *(const bf16x8*)(Xs + b * 1024 + ((((ks + 1) << 6) + (l4 << 4)) ^ ((b & 7) << 4)));
        }
      }
#pragma unroll
      for (int hf = 0; hf < 2; ++hf)
#pragma unroll
        for (int bf = 0; bf < 5; ++bf)
          acc[hf][bf] = __builtin_amdgcn_mfma_f32_16x16x32_bf16(A[ks & 1][hf], Bc[bf], acc[hf][bf], 0, 0, 0);
      if (ks < 14) {
#pragma unroll
        for (int hf = 0; hf < 2; ++hf)
          A[ks & 1][hf] = *(const bf16x8*)(Wl + (hf << 14) + ((ks + 2) << 10));
      }
#pragma unroll
      for (int bf = 0; bf < 5; ++bf) Bc[bf] = Bn[bf];
    }
    // layer-2 A preloads; latency hides under epilogue + barriers
#pragma unroll
    for (int s = 0; s < 2; ++s)
#pragma unroll
      for (int hf = 0; hf < 2; ++hf)
        A[s][hf] = *(const bf16x8*)(Wl2 + (hf << 14) + (s << 10));
    // epilogue: bias + relu + pack bf16 into registers
#pragma unroll
    for (int hf = 0; hf < 2; ++hf) {
      int hb = (w << 5) + (hf << 4) + (l4 << 2);
      float4 bias = *(const float4*)(b1 + (a << 9) + hb);
#pragma unroll
      for (int bf = 0; bf < 5; ++bf) {
        float x0 = fmaxf(acc[hf][bf][0] + bias.x, 0.f);
        float x1 = fmaxf(acc[hf][bf][1] + bias.y, 0.f);
        float x2 = fmaxf(acc[hf][bf][2] + bias.z, 0.f);
        float x3 = fmaxf(acc[hf][bf][3] + bias.w, 0.f);
        h1p[hf * 5 + bf].x = (unsigned)f2b(x0) | ((unsigned)f2b(x1) << 16);
        h1p[hf * 5 + bf].y = (unsigned)f2b(x2) | ((unsigned)f2b(x3) << 16);
      }
    }
  }
  __syncthreads();  // all waves done reading X
#pragma unroll
  for (int hf = 0; hf < 2; ++hf) {
    int hb2 = ((w << 5) + (hf << 4) + (l4 << 2)) << 1;  // byte offset within row
#pragma unroll
    for (int bf = 0; bf < 5; ++bf) {
      int b = (bf << 4) + l15;
      *(uint2*)(Xs + b * 1024 + (hb2 ^ ((b & 7) << 4))) = h1p[hf * 5 + bf];
    }
  }
  __syncthreads();

  // ---- layer 2 + fused layer 3: out = relu(h1 @ W2 + b2) . W3 + b3 ----
  {
    f32x4 acc[2][5] = {};
#pragma unroll
    for (int bf = 0; bf < 5; ++bf) {
      int b = (bf << 4) + l15;
      Bc[bf] = *(const bf16x8*)(Xs + b * 1024 + ((l4 << 4) ^ ((b & 7) << 4)));
    }
#pragma unroll
    for (int ks = 0; ks < 16; ++ks) {
      if (ks < 15) {
#pragma unroll
        for (int bf = 0; bf < 5; ++bf) {
          int b = (bf << 4) + l15;
          Bn[bf] = *(const bf16x8*)(Xs + b * 1024 + ((((ks + 1) << 6) + (l4 << 4)) ^ ((b & 7) << 4)));
        }
      }
#pragma unroll
      for (int hf = 0; hf < 2; ++hf)
#pragma unroll
        for (int bf = 0; bf < 5; ++bf)
          acc[hf][bf] = __builtin_amdgcn_mfma_f32_16x16x32_bf16(A[ks & 1][hf], Bc[bf], acc[hf][bf], 0, 0, 0);
      if (ks < 14) {
#pragma unroll
        for (int hf = 0; hf < 2; ++hf)
          A[ks & 1][hf] = *(const bf16x8*)(Wl2 + (hf << 14) + ((ks + 2) << 10));
      }
#pragma unroll
      for (int bf = 0; bf < 5; ++bf) Bc[bf] = Bn[bf];
    }
    float part[5] = {0.f, 0.f, 0.f, 0.f, 0.f};
#pragma unroll
    for (int hf = 0; hf < 2; ++hf) {
      int hb = (w << 5) + (hf << 4) + (l4 << 2);
      float4 bias = *(const float4*)(b2 + (a << 9) + hb);
      float4 w3v = *(const float4*)(W3 + (a << 9) + hb);
#pragma unroll
      for (int bf = 0; bf < 5; ++bf) {
        part[bf] += fmaxf(acc[hf][bf][0] + bias.x, 0.f) * w3v.x +
                    fmaxf(acc[hf][bf][1] + bias.y, 0.f) * w3v.y +
                    fmaxf(acc[hf][bf][2] + bias.z, 0.f) * w3v.z +
                    fmaxf(acc[hf][bf][3] + bias.w, 0.f) * w3v.w;
      }
    }
#pragma unroll
    for (int bf = 0; bf < 5; ++bf) {
      float p = part[bf];
      p += __shfl_xor(p, 16);
      p += __shfl_xor(p, 32);
      if (l4 == 0) outbuf[w * TR + (bf << 4) + l15] = p;
    }
  }
  __syncthreads();
  if (tid < nrows) {
    float s = b3[a];
#pragma unroll
    for (int ww = 0; ww < 16; ++ww) s += outbuf[ww * TR + tid];
    out[perm[rowbase + tid]] = s;
  }
}

extern "C" void kernel_launch(void* const* d_in, const int* in_sizes, int n_in,
                              void* d_out, int out_size, void* d_ws, size_t ws_size,
                              hipStream_t stream) {
  const float* state = (const float*)d_in[0];
  const float* W1 = (const float*)d_in[1];
  const float* b1 = (const float*)d_in[2];
  const float* W2 = (const float*)d_in[3];
  const float* b2 = (const float*)d_in[4];
  const float* W3 = (const float*)d_in[5];
  const float* b3 = (const float*)d_in[6];
  const int* actions = (const int*)d_in[7];
  float* out = (float*)d_out;
  char* ws = (char*)d_ws;
  bf16* W1s = (bf16*)(ws + W1S_OFF);
  bf16* W2s = (bf16*)(ws + W2S_OFF);
  int* perm = (int*)(ws + PERM_OFF);
  int* meta = (int*)(ws + META_OFF);

  k_prep<<<2049, 256, 0, stream>>>(W1, W2, W1s, W2s, actions, meta, perm);
  hipFuncSetAttribute((const void*)k_main, hipFuncAttributeMaxDynamicSharedMemorySize, 87040);
  k_main<<<256, 1024, 87040, stream>>>(state, b1, b2, W3, b3, W1s, W2s, perm, meta, out);
}